// Round 21
// baseline (2448.917 us; speedup 1.0000x reference)
//
#include <hip/hip_runtime.h>
#include <hip/hip_bf16.h>
#include <math.h>

// Problem constants
#define NN 50000
#define NNP 50048       // rows padded to multiple of 128 (planes sized off this)
#define NE 800000
#define DD 256
#define NSTEPS 6

#define BK 32

typedef unsigned short u16;
typedef _Float16 f16x8 __attribute__((ext_vector_type(8)));
typedef _Float16 f16x4 __attribute__((ext_vector_type(4)));
typedef float f32x4 __attribute__((ext_vector_type(4)));

__device__ __forceinline__ float sigmoidf_(float v) {
    return 1.0f / (1.0f + expf(-v));
}
// fast transcendentals (epilogue only; err ~1e-7, negligible vs fp16 injections)
__device__ __forceinline__ float fsig(float v) {
    return __builtin_amdgcn_rcpf(1.0f + __expf(-v));
}
__device__ __forceinline__ float ftanh_(float v) {
    return 1.0f - 2.0f * __builtin_amdgcn_rcpf(1.0f + __expf(2.0f * v));
}
__device__ __forceinline__ u16 f2h(float v) {
    _Float16 h = (_Float16)v;            // RNE
    u16 u; __builtin_memcpy(&u, &h, 2); return u;
}
__device__ __forceinline__ float h2f(u16 u) {
    _Float16 h; __builtin_memcpy(&h, &u, 2); return (float)h;
}
// fp16 2-way split: v ~= h + l to 2^-22 relative
__device__ __forceinline__ void split2(float v, u16& h, u16& l) {
    h = f2h(v);
    float r = v - h2f(h);
    l = f2h(r);
}
__device__ __forceinline__ unsigned pk(u16 a, u16 b) {
    return (unsigned)a | ((unsigned)b << 16);
}
__device__ __forceinline__ void store_planes(u16* base, size_t ps, size_t off, float v) {
    u16 h, l; split2(v, h, l);
    base[off] = h; base[ps + off] = l;
}
__device__ __forceinline__ void gload16(const void* g, void* l) {
    __builtin_amdgcn_global_load_lds(
        (const __attribute__((address_space(1))) void*)g,
        (__attribute__((address_space(3))) void*)l, 16, 0, 0);
}

// ---------------- CSR build (verified R1-R20) ----------------

__global__ void zero_kernel(int* __restrict__ p, int n) {
    int i = blockIdx.x * blockDim.x + threadIdx.x;
    if (i < n) p[i] = 0;
}
__global__ void hist_kernel(const int* __restrict__ dst, int* __restrict__ counts, int E) {
    int e = blockIdx.x * blockDim.x + threadIdx.x;
    if (e < E) atomicAdd(&counts[dst[e]], 1);
}
__global__ void scan_kernel(const int* __restrict__ counts, int* __restrict__ row_ptr, int n) {
    __shared__ int buf[1024];
    __shared__ int carry;
    const int tid = threadIdx.x;
    if (tid == 0) carry = 0;
    __syncthreads();
    for (int base = 0; base < n; base += 1024) {
        int i = base + tid;
        int v = (i < n) ? counts[i] : 0;
        buf[tid] = v;
        __syncthreads();
        for (int off = 1; off < 1024; off <<= 1) {
            int t = (tid >= off) ? buf[tid - off] : 0;
            __syncthreads();
            buf[tid] += t;
            __syncthreads();
        }
        if (i < n) row_ptr[i] = carry + buf[tid] - v;
        __syncthreads();
        if (tid == 0) carry += buf[1023];
        __syncthreads();
    }
    if (threadIdx.x == 0) row_ptr[n] = carry;
}
__global__ void fill_kernel(const int* __restrict__ src, const int* __restrict__ dst,
                            const int* __restrict__ row_ptr, int* __restrict__ cursor,
                            int* __restrict__ csr_src, int E) {
    int e = blockIdx.x * blockDim.x + threadIdx.x;
    if (e < E) {
        int d = dst[e];
        int p = atomicAdd(&cursor[d], 1);
        csr_src[row_ptr[d] + p] = src[e];
    }
}

// ---------------- fp32 -> 2 fp16 planes (rows padded w/ zero) ----------------
__global__ void split_rows(const float* __restrict__ src, u16* __restrict__ dst,
                           size_t pstride, int srcRows) {
    int row = blockIdx.x;
    int col = threadIdx.x;
    size_t off = (size_t)row * DD + col;
    float v = (row < srcRows) ? src[off] : 0.0f;
    store_planes(dst, pstride, off, v);
}

// ---------------- fp32 -> single fp16 plane ----------------
__global__ void half_rows(const float* __restrict__ src, u16* __restrict__ dst) {
    int row = blockIdx.x;
    int col = threadIdx.x;
    size_t off = (size_t)row * DD + col;
    dst[off] = f2h(src[off]);
}

// ---------------- fused MLP, 1-term products (R18 champion, 32-row blocks) ----------------
__global__ __launch_bounds__(256, 3)
void mlp_fused(const u16* __restrict__ pX,
               const u16* __restrict__ W1H, const u16* __restrict__ W2H,
               const float* __restrict__ b1, const float* __restrict__ b2,
               u16* __restrict__ HP, int M) {
    __shared__ u16 lds[17408];
    const int T1B = 9216;

    const int tid = threadIdx.x;
    const int lane = tid & 63;
    const int wv = tid >> 6;           // col quarter 0..3
    const int frow = lane & 15;
    const int kg = lane >> 4;
    const int rowBase = blockIdx.x * 32;

    int offj[5]; int ldsj[5]; bool isWj[5]; bool actj[5];
#pragma unroll
    for (int j = 0; j < 5; ++j) {
        int q = wv * 5 + j;
        actj[j] = q < 18;
        bool isW = q >= 2;
        int row, ldso, eoff = 0;
        if (q < 2) {
            row = q * 16 + (lane >> 2);
            int chunk = (lane & 3) ^ ((row >> 1) & 3);
            eoff = (rowBase + row) * DD + chunk * 8;
            ldso = q * 512;
        } else {
            int qw = (q - 2) & 15;
            row = qw * 16 + (lane >> 2);
            int chunk = (lane & 3) ^ ((row >> 1) & 3);
            eoff = row * DD + chunk * 8;
            ldso = 1024 + qw * 512;
        }
        offj[j] = eoff; ldsj[j] = ldso; isWj[j] = isW;
    }

    // phase 1: t1 = ReLU(xh @ W1h^T + b1)
    f32x4 acc1[2][4] = {};
    for (int kc = 0; kc < DD; kc += BK) {
#pragma unroll
        for (int j = 0; j < 5; ++j)
            if (actj[j]) gload16((isWj[j] ? W1H : pX) + offj[j] + kc, &lds[ldsj[j]]);
        __syncthreads();

        f16x8 af[2];
#pragma unroll
        for (int mf = 0; mf < 2; ++mf) {
            int row = mf * 16 + frow;
            af[mf] = *reinterpret_cast<const f16x8*>(
                &lds[row * 32 + ((kg ^ ((row >> 1) & 3)) * 8)]);
        }
#pragma unroll
        for (int nf = 0; nf < 4; ++nf) {
            int brow = wv * 64 + nf * 16 + frow;
            int boff = 1024 + brow * 32 + ((kg ^ ((brow >> 1) & 3)) * 8);
            f16x8 bh = *reinterpret_cast<const f16x8*>(&lds[boff]);
#pragma unroll
            for (int mf = 0; mf < 2; ++mf)
                acc1[mf][nf] = __builtin_amdgcn_mfma_f32_16x16x32_f16(
                    af[mf], bh, acc1[mf][nf], 0, 0, 0);
        }
        __syncthreads();
    }

    // t1 -> LDS fp16 (swizzled: chunk index XOR (row&7))
#pragma unroll
    for (int nf = 0; nf < 4; ++nf) {
        int col = wv * 64 + nf * 16 + frow;
        float bb = b1[col];
        int c8 = col >> 3, ci = col & 7;
#pragma unroll
        for (int mf = 0; mf < 2; ++mf) {
#pragma unroll
            for (int j = 0; j < 4; ++j) {
                int row = mf * 16 + kg * 4 + j;
                float v = fmaxf(acc1[mf][nf][j] + bb, 0.0f);
                lds[T1B + row * 256 + ((c8 ^ (row & 7)) * 8) + ci] = f2h(v);
            }
        }
    }
    __syncthreads();

    // phase 2: h = t1 @ W2h^T + b2 (1-term)
    f32x4 acc2[2][4] = {};
    for (int kc = 0; kc < DD; kc += BK) {
#pragma unroll
        for (int j = 0; j < 5; ++j)
            if (actj[j] && isWj[j]) gload16(W2H + offj[j] + kc, &lds[ldsj[j]]);
        __syncthreads();

        f16x8 at[2];
#pragma unroll
        for (int mf = 0; mf < 2; ++mf) {
            int row = mf * 16 + frow;
            int qc = (kc >> 3) + kg;
            at[mf] = *reinterpret_cast<const f16x8*>(
                &lds[T1B + row * 256 + ((qc ^ (row & 7)) * 8)]);
        }
#pragma unroll
        for (int nf = 0; nf < 4; ++nf) {
            int brow = wv * 64 + nf * 16 + frow;
            int boff = 1024 + brow * 32 + ((kg ^ ((brow >> 1) & 3)) * 8);
            f16x8 bh = *reinterpret_cast<const f16x8*>(&lds[boff]);
#pragma unroll
            for (int mf = 0; mf < 2; ++mf)
                acc2[mf][nf] = __builtin_amdgcn_mfma_f32_16x16x32_f16(
                    at[mf], bh, acc2[mf][nf], 0, 0, 0);
        }
        __syncthreads();
    }

#pragma unroll
    for (int nf = 0; nf < 4; ++nf) {
        int col = wv * 64 + nf * 16 + frow;
        float bb = b2[col];
#pragma unroll
        for (int mf = 0; mf < 2; ++mf) {
#pragma unroll
            for (int j = 0; j < 4; ++j) {
                int gr = rowBase + mf * 16 + kg * 4 + j;
                if (gr < M) HP[(size_t)gr * DD + col] = f2h(acc2[mf][nf][j] + bb);
            }
        }
    }
}

// ---------------- fused GRU: BM=256, 1024 threads, staged-volume-minimized ----------------
// B panels (75% of staged bytes) amortized over 256 rows/block: staged volume
// 400 -> 250 MB per dispatch (volume law predicts ~97 us vs 137).
// Per-wave tile 64x32 (identical accumulator state to R18 -> no VGPR change).
// Ragged tail rows (>=NN, up to 50175) read in-ws garbage, masked at store.
template <bool FINAL>
__global__ __launch_bounds__(1024, 1)
void gru_fused(const u16* __restrict__ pMsgH, const u16* __restrict__ pX, size_t psA,
               const u16* __restrict__ pWihH, const u16* __restrict__ pWhhH,
               const float* __restrict__ bih, const float* __restrict__ bhh,
               float* __restrict__ outF, u16* __restrict__ outP, size_t psO, int M) {
    // Per k-subtile (20480 u16 = 40 KB): A_h [256][32] @0 (8192);
    // B panels @8192+gate*4096 (r,z,n hi, each [128][32]). Two subtiles = 80 KB.
    __shared__ u16 lds[40960];

    const int tid = threadIdx.x;
    const int lane = tid & 63;
    const int wv = tid >> 6;           // 0..15
    const int wr = wv >> 2;            // 0..3 (64-row group)
    const int wc = wv & 3;             // 0..3 (32-col quarter)
    const int frow = lane & 15;
    const int kg = lane >> 4;
    const int rowBase = blockIdx.x * 256;
    const int colBase = blockIdx.y * 128;

    // staging per subtile: 40 x 1KB issues over 16 waves (up to 3 per wave).
    // q = j*16 + wv; q<16: A sub q; q in [16,40): qb=q-16: gate qb>>3, sub qb&7.
    int offj[3]; int ldsj[3]; bool actj[3];
#pragma unroll
    for (int j = 0; j < 3; ++j) {
        int q = j * 16 + wv;
        actj[j] = q < 40;
        int eoff = 0, ldso = 0;
        if (q < 16) {
            int row = q * 16 + (lane >> 2);
            int chunk = (lane & 3) ^ ((row >> 1) & 3);
            eoff = (rowBase + row) * DD + chunk * 8;
            ldso = q * 512;
        } else if (q < 40) {
            int qb = q - 16;                 // 0..23
            int gate = qb >> 3;              // 0:r 1:z 2:n
            int sub = qb & 7;
            int row = sub * 16 + (lane >> 2);
            int chunk = (lane & 3) ^ ((row >> 1) & 3);
            eoff = (gate * 256 + colBase + row) * DD + chunk * 8;
            ldso = 8192 + qb * 512;
        }
        offj[j] = eoff; ldsj[j] = ldso;
    }
    // per-issue source selector: A (q<16) vs B
    bool isBj[3];
#pragma unroll
    for (int j = 0; j < 3; ++j) isBj[j] = (j * 16 + wv) >= 16;

    f32x4 accr[4][2] = {};
    f32x4 accz[4][2] = {};
    f32x4 accx[4][2] = {};
    f32x4 acch[4][2] = {};

#pragma unroll
    for (int half = 0; half < 2; ++half) {
        const u16* Ab = half ? pX : pMsgH;     // hi plane only
        const u16* Bb = half ? pWhhH : pWihH;  // hi plane only
        for (int kc = 0; kc < DD; kc += 2 * BK) {
#pragma unroll
            for (int j = 0; j < 3; ++j)
                if (actj[j]) gload16((isBj[j] ? Bb : Ab) + offj[j] + kc, &lds[ldsj[j]]);
#pragma unroll
            for (int j = 0; j < 3; ++j)
                if (actj[j]) gload16((isBj[j] ? Bb : Ab) + offj[j] + kc + BK,
                                     &lds[20480 + ldsj[j]]);
            __syncthreads();

#pragma unroll
            for (int st = 0; st < 2; ++st) {
                const u16* L = &lds[st * 20480];
                f16x8 af[4];
#pragma unroll
                for (int mf = 0; mf < 4; ++mf) {
                    int row = wr * 64 + mf * 16 + frow;
                    af[mf] = *reinterpret_cast<const f16x8*>(
                        &L[row * 32 + ((kg ^ ((row >> 1) & 3)) * 8)]);
                }
#pragma unroll
                for (int nf = 0; nf < 2; ++nf) {
                    int brow = wc * 32 + nf * 16 + frow;
                    int bsw = brow * 32 + ((kg ^ ((brow >> 1) & 3)) * 8);
                    f16x8 brh = *reinterpret_cast<const f16x8*>(&L[8192 + bsw]);
                    f16x8 bzh = *reinterpret_cast<const f16x8*>(&L[12288 + bsw]);
                    f16x8 bnh = *reinterpret_cast<const f16x8*>(&L[16384 + bsw]);
#pragma unroll
                    for (int mf = 0; mf < 4; ++mf) {
                        accr[mf][nf] = __builtin_amdgcn_mfma_f32_16x16x32_f16(
                            af[mf], brh, accr[mf][nf], 0, 0, 0);
                        accz[mf][nf] = __builtin_amdgcn_mfma_f32_16x16x32_f16(
                            af[mf], bzh, accz[mf][nf], 0, 0, 0);
                        f32x4 cn = (half == 0) ? accx[mf][nf] : acch[mf][nf];
                        cn = __builtin_amdgcn_mfma_f32_16x16x32_f16(af[mf], bnh, cn, 0, 0, 0);
                        if (half == 0) accx[mf][nf] = cn; else acch[mf][nf] = cn;
                    }
                }
            }
            __syncthreads();
        }
    }

    // epilogue: full GRU update (fast transcendentals; x blend from both planes)
#pragma unroll
    for (int nf = 0; nf < 2; ++nf) {
        int gc = colBase + wc * 32 + nf * 16 + frow;
        float br = bih[gc] + bhh[gc];
        float bz = bih[256 + gc] + bhh[256 + gc];
        float bx = bih[512 + gc];
        float bh = bhh[512 + gc];
#pragma unroll
        for (int mf = 0; mf < 4; ++mf) {
#pragma unroll
            for (int j = 0; j < 4; ++j) {
                int gr = rowBase + wr * 64 + mf * 16 + kg * 4 + j;
                if (gr < M) {
                    size_t off = (size_t)gr * DD + gc;
                    float r = fsig(accr[mf][nf][j] + br);
                    float z = fsig(accz[mf][nf][j] + bz);
                    float T = ftanh_(accx[mf][nf][j] + bx + r * (acch[mf][nf][j] + bh));
                    float x = h2f(pX[off]) + h2f(pX[psA + off]);
                    float o = (1.0f - z) * T + z * x;
                    if (FINAL) outF[off] = o;
                    else       store_planes(outP, psO, off, o);
                }
            }
        }
    }
}

// ---------------- segment sum -> msg single fp16 plane ----------------
__global__ __launch_bounds__(256)
void segsum_kernel(const u16* __restrict__ hp, const int* __restrict__ row_ptr,
                   const int* __restrict__ csr_src, u16* __restrict__ msgH, int n) {
    int node = blockIdx.x * 4 + threadIdx.y;
    if (node >= n) return;
    int d4 = threadIdx.x * 4;
    int s = row_ptr[node];
    int e = row_ptr[node + 1];
    float4 acc = make_float4(0.f, 0.f, 0.f, 0.f);
    for (int j = s; j < e; ++j) {
        int sn = csr_src[j];
        f16x4 v = *reinterpret_cast<const f16x4*>(&hp[(size_t)sn * DD + d4]);
        acc.x += (float)v[0]; acc.y += (float)v[1];
        acc.z += (float)v[2]; acc.w += (float)v[3];
    }
    size_t off = (size_t)node * DD + d4;
    *reinterpret_cast<uint2*>(&msgH[off]) =
        make_uint2(pk(f2h(acc.x), f2h(acc.y)), pk(f2h(acc.z), f2h(acc.w)));
}

// ---------------- launch ----------------

extern "C" void kernel_launch(void* const* d_in, const int* in_sizes, int n_in,
                              void* d_out, int out_size, void* d_ws, size_t ws_size,
                              hipStream_t stream) {
    const float* x0  = (const float*)d_in[0];
    const float* W1  = (const float*)d_in[1];
    const float* b1  = (const float*)d_in[2];
    const float* W2  = (const float*)d_in[3];
    const float* b2  = (const float*)d_in[4];
    const float* Wih = (const float*)d_in[5];
    const float* bih = (const float*)d_in[6];
    const float* Whh = (const float*)d_in[7];
    const float* bhh = (const float*)d_in[8];
    const int*   src = (const int*)d_in[9];
    const int*   dst = (const int*)d_in[10];

    // workspace layout (<= proven 211.3 MB footprint)
    char* ws = (char*)d_ws;
    const size_t PSA = (size_t)NNP * DD;
    const size_t SP  = PSA * 2 * sizeof(u16);
    const size_t NB  = PSA * sizeof(float);
    const size_t PSW2 = (size_t)DD * DD;
    const size_t PSW3 = (size_t)3 * DD * DD;
    u16* XP0   = (u16*)(ws);
    u16* XP1   = (u16*)(ws + SP);
    u16* TP    = (u16*)(ws + 2 * SP);       // msg single fp16 plane
    u16* HP    = (u16*)(ws + 3 * SP);       // h single fp16 plane
    u16* W1H   = (u16*)(ws + 3 * SP + NB);  // hi-plane-only weights
    u16* W2H   = W1H + PSW2;
    u16* WIHH  = W2H + PSW2;
    u16* WHHH  = WIHH + PSW3;
    int* counts  = (int*)(WHHH + PSW3);
    int* cursor  = counts + NN;
    int* row_ptr = cursor + NN;
    int* csr     = row_ptr + NN + 8;
    const size_t needed = 3 * SP + NB + (2 * PSW2 + 2 * PSW3) * sizeof(u16)
                        + (size_t)(2 * NN + NN + 9 + NE) * sizeof(int);
    if (ws_size < needed) return;

    float* FOUT = (float*)d_out;

    // CSR build
    zero_kernel<<<(2 * NN + 255) / 256, 256, 0, stream>>>(counts, 2 * NN);
    hist_kernel<<<(NE + 255) / 256, 256, 0, stream>>>(dst, counts, NE);
    scan_kernel<<<1, 1024, 0, stream>>>(counts, row_ptr, NN);
    fill_kernel<<<(NE + 255) / 256, 256, 0, stream>>>(src, dst, row_ptr, cursor, csr, NE);

    // weights: hi plane only; x0: 2-plane split
    half_rows<<<DD, 256, 0, stream>>>(W1, W1H);
    half_rows<<<DD, 256, 0, stream>>>(W2, W2H);
    half_rows<<<3 * DD, 256, 0, stream>>>(Wih, WIHH);
    half_rows<<<3 * DD, 256, 0, stream>>>(Whh, WHHH);
    split_rows<<<NNP, 256, 0, stream>>>(x0, XP0, PSA, NN);

    const dim3 gridGRU((NNP + 255) / 256, 2);   // 196 x 2, 1024-thread blocks

    for (int s = 0; s < NSTEPS; ++s) {
        u16* XPc = (s & 1) ? XP1 : XP0;
        u16* XPn = (s & 1) ? XP0 : XP1;

        // h = MLP(x) -> HP (single fp16 plane)
        mlp_fused<<<NNP / 32, 256, 0, stream>>>(
            XPc, W1H, W2H, b1, b2, HP, NN);
        // msg = segment_sum(h[src], dst) -> TP (single fp16 plane)
        segsum_kernel<<<dim3((NN + 3) / 4), dim3(64, 4), 0, stream>>>(
            HP, row_ptr, csr, TP, NN);
        // full GRU update -> x_next planes (final: fp32 d_out)
        if (s < NSTEPS - 1) {
            gru_fused<false><<<gridGRU, 1024, 0, stream>>>(
                TP, XPc, PSA, WIHH, WHHH, bih, bhh,
                nullptr, XPn, PSA, NN);
        } else {
            gru_fused<true><<<gridGRU, 1024, 0, stream>>>(
                TP, XPc, PSA, WIHH, WHHH, bih, bhh,
                FOUT, nullptr, 0, NN);
        }
    }
}

// Round 22
// 2441.522 us; speedup vs baseline: 1.0030x; 1.0030x over previous
//
#include <hip/hip_runtime.h>
#include <hip/hip_bf16.h>
#include <math.h>

// Problem constants
#define NN 50000
#define NNP 50048       // rows padded to multiple of 128 (planes sized off this)
#define NE 800000
#define DD 256
#define NSTEPS 6

#define BK 32

typedef unsigned short u16;
typedef _Float16 f16x8 __attribute__((ext_vector_type(8)));
typedef _Float16 f16x4 __attribute__((ext_vector_type(4)));
typedef float f32x4 __attribute__((ext_vector_type(4)));

__device__ __forceinline__ float sigmoidf_(float v) {
    return 1.0f / (1.0f + expf(-v));
}
// fast transcendentals (epilogue only; err ~1e-7, negligible vs fp16 injections)
__device__ __forceinline__ float fsig(float v) {
    return __builtin_amdgcn_rcpf(1.0f + __expf(-v));
}
__device__ __forceinline__ float ftanh_(float v) {
    return 1.0f - 2.0f * __builtin_amdgcn_rcpf(1.0f + __expf(2.0f * v));
}
__device__ __forceinline__ u16 f2h(float v) {
    _Float16 h = (_Float16)v;            // RNE
    u16 u; __builtin_memcpy(&u, &h, 2); return u;
}
__device__ __forceinline__ float h2f(u16 u) {
    _Float16 h; __builtin_memcpy(&h, &u, 2); return (float)h;
}
// fp16 2-way split: v ~= h + l to 2^-22 relative
__device__ __forceinline__ void split2(float v, u16& h, u16& l) {
    h = f2h(v);
    float r = v - h2f(h);
    l = f2h(r);
}
__device__ __forceinline__ unsigned pk(u16 a, u16 b) {
    return (unsigned)a | ((unsigned)b << 16);
}
__device__ __forceinline__ void store_planes(u16* base, size_t ps, size_t off, float v) {
    u16 h, l; split2(v, h, l);
    base[off] = h; base[ps + off] = l;
}
__device__ __forceinline__ void gload16(const void* g, void* l) {
    __builtin_amdgcn_global_load_lds(
        (const __attribute__((address_space(1))) void*)g,
        (__attribute__((address_space(3))) void*)l, 16, 0, 0);
}

// ---------------- CSR build (verified R1-R21) ----------------

__global__ void zero_kernel(int* __restrict__ p, int n) {
    int i = blockIdx.x * blockDim.x + threadIdx.x;
    if (i < n) p[i] = 0;
}
__global__ void hist_kernel(const int* __restrict__ dst, int* __restrict__ counts, int E) {
    int e = blockIdx.x * blockDim.x + threadIdx.x;
    if (e < E) atomicAdd(&counts[dst[e]], 1);
}
__global__ void scan_kernel(const int* __restrict__ counts, int* __restrict__ row_ptr, int n) {
    __shared__ int buf[1024];
    __shared__ int carry;
    const int tid = threadIdx.x;
    if (tid == 0) carry = 0;
    __syncthreads();
    for (int base = 0; base < n; base += 1024) {
        int i = base + tid;
        int v = (i < n) ? counts[i] : 0;
        buf[tid] = v;
        __syncthreads();
        for (int off = 1; off < 1024; off <<= 1) {
            int t = (tid >= off) ? buf[tid - off] : 0;
            __syncthreads();
            buf[tid] += t;
            __syncthreads();
        }
        if (i < n) row_ptr[i] = carry + buf[tid] - v;
        __syncthreads();
        if (tid == 0) carry += buf[1023];
        __syncthreads();
    }
    if (threadIdx.x == 0) row_ptr[n] = carry;
}
__global__ void fill_kernel(const int* __restrict__ src, const int* __restrict__ dst,
                            const int* __restrict__ row_ptr, int* __restrict__ cursor,
                            int* __restrict__ csr_src, int E) {
    int e = blockIdx.x * blockDim.x + threadIdx.x;
    if (e < E) {
        int d = dst[e];
        int p = atomicAdd(&cursor[d], 1);
        csr_src[row_ptr[d] + p] = src[e];
    }
}

// ---------------- fp32 -> 2 fp16 planes (rows padded w/ zero) ----------------
__global__ void split_rows(const float* __restrict__ src, u16* __restrict__ dst,
                           size_t pstride, int srcRows) {
    int row = blockIdx.x;
    int col = threadIdx.x;
    size_t off = (size_t)row * DD + col;
    float v = (row < srcRows) ? src[off] : 0.0f;
    store_planes(dst, pstride, off, v);
}

// ---------------- fp32 -> single fp16 plane ----------------
__global__ void half_rows(const float* __restrict__ src, u16* __restrict__ dst) {
    int row = blockIdx.x;
    int col = threadIdx.x;
    size_t off = (size_t)row * DD + col;
    dst[off] = f2h(src[off]);
}

// ---------------- fused MLP, 1-term products (R18 champion, 32-row blocks) ----------------
__global__ __launch_bounds__(256, 3)
void mlp_fused(const u16* __restrict__ pX,
               const u16* __restrict__ W1H, const u16* __restrict__ W2H,
               const float* __restrict__ b1, const float* __restrict__ b2,
               u16* __restrict__ HP, int M) {
    __shared__ u16 lds[17408];
    const int T1B = 9216;

    const int tid = threadIdx.x;
    const int lane = tid & 63;
    const int wv = tid >> 6;           // col quarter 0..3
    const int frow = lane & 15;
    const int kg = lane >> 4;
    const int rowBase = blockIdx.x * 32;

    int offj[5]; int ldsj[5]; bool isWj[5]; bool actj[5];
#pragma unroll
    for (int j = 0; j < 5; ++j) {
        int q = wv * 5 + j;
        actj[j] = q < 18;
        bool isW = q >= 2;
        int row, ldso, eoff = 0;
        if (q < 2) {
            row = q * 16 + (lane >> 2);
            int chunk = (lane & 3) ^ ((row >> 1) & 3);
            eoff = (rowBase + row) * DD + chunk * 8;
            ldso = q * 512;
        } else {
            int qw = (q - 2) & 15;
            row = qw * 16 + (lane >> 2);
            int chunk = (lane & 3) ^ ((row >> 1) & 3);
            eoff = row * DD + chunk * 8;
            ldso = 1024 + qw * 512;
        }
        offj[j] = eoff; ldsj[j] = ldso; isWj[j] = isW;
    }

    // phase 1: t1 = ReLU(xh @ W1h^T + b1)
    f32x4 acc1[2][4] = {};
    for (int kc = 0; kc < DD; kc += BK) {
#pragma unroll
        for (int j = 0; j < 5; ++j)
            if (actj[j]) gload16((isWj[j] ? W1H : pX) + offj[j] + kc, &lds[ldsj[j]]);
        __syncthreads();

        f16x8 af[2];
#pragma unroll
        for (int mf = 0; mf < 2; ++mf) {
            int row = mf * 16 + frow;
            af[mf] = *reinterpret_cast<const f16x8*>(
                &lds[row * 32 + ((kg ^ ((row >> 1) & 3)) * 8)]);
        }
#pragma unroll
        for (int nf = 0; nf < 4; ++nf) {
            int brow = wv * 64 + nf * 16 + frow;
            int boff = 1024 + brow * 32 + ((kg ^ ((brow >> 1) & 3)) * 8);
            f16x8 bh = *reinterpret_cast<const f16x8*>(&lds[boff]);
#pragma unroll
            for (int mf = 0; mf < 2; ++mf)
                acc1[mf][nf] = __builtin_amdgcn_mfma_f32_16x16x32_f16(
                    af[mf], bh, acc1[mf][nf], 0, 0, 0);
        }
        __syncthreads();
    }

    // t1 -> LDS fp16 (swizzled: chunk index XOR (row&7))
#pragma unroll
    for (int nf = 0; nf < 4; ++nf) {
        int col = wv * 64 + nf * 16 + frow;
        float bb = b1[col];
        int c8 = col >> 3, ci = col & 7;
#pragma unroll
        for (int mf = 0; mf < 2; ++mf) {
#pragma unroll
            for (int j = 0; j < 4; ++j) {
                int row = mf * 16 + kg * 4 + j;
                float v = fmaxf(acc1[mf][nf][j] + bb, 0.0f);
                lds[T1B + row * 256 + ((c8 ^ (row & 7)) * 8) + ci] = f2h(v);
            }
        }
    }
    __syncthreads();

    // phase 2: h = t1 @ W2h^T + b2 (1-term)
    f32x4 acc2[2][4] = {};
    for (int kc = 0; kc < DD; kc += BK) {
#pragma unroll
        for (int j = 0; j < 5; ++j)
            if (actj[j] && isWj[j]) gload16(W2H + offj[j] + kc, &lds[ldsj[j]]);
        __syncthreads();

        f16x8 at[2];
#pragma unroll
        for (int mf = 0; mf < 2; ++mf) {
            int row = mf * 16 + frow;
            int qc = (kc >> 3) + kg;
            at[mf] = *reinterpret_cast<const f16x8*>(
                &lds[T1B + row * 256 + ((qc ^ (row & 7)) * 8)]);
        }
#pragma unroll
        for (int nf = 0; nf < 4; ++nf) {
            int brow = wv * 64 + nf * 16 + frow;
            int boff = 1024 + brow * 32 + ((kg ^ ((brow >> 1) & 3)) * 8);
            f16x8 bh = *reinterpret_cast<const f16x8*>(&lds[boff]);
#pragma unroll
            for (int mf = 0; mf < 2; ++mf)
                acc2[mf][nf] = __builtin_amdgcn_mfma_f32_16x16x32_f16(
                    at[mf], bh, acc2[mf][nf], 0, 0, 0);
        }
        __syncthreads();
    }

#pragma unroll
    for (int nf = 0; nf < 4; ++nf) {
        int col = wv * 64 + nf * 16 + frow;
        float bb = b2[col];
#pragma unroll
        for (int mf = 0; mf < 2; ++mf) {
#pragma unroll
            for (int j = 0; j < 4; ++j) {
                int gr = rowBase + mf * 16 + kg * 4 + j;
                if (gr < M) HP[(size_t)gr * DD + col] = f2h(acc2[mf][nf][j] + bb);
            }
        }
    }
}

// ---------------- fused GRU: BM=256, 1024 threads, VGPR budget pinned ----------------
// __launch_bounds__(1024, 4): min 4 waves/EU = the full 16-wave block resident
// -> VGPR cap 128 (need ~108, proven non-spilling at that budget in R18).
// B panels amortized over 256 rows/block: staged volume 400 -> 250 MB/dispatch.
template <bool FINAL>
__global__ __launch_bounds__(1024, 4)
void gru_fused(const u16* __restrict__ pMsgH, const u16* __restrict__ pX, size_t psA,
               const u16* __restrict__ pWihH, const u16* __restrict__ pWhhH,
               const float* __restrict__ bih, const float* __restrict__ bhh,
               float* __restrict__ outF, u16* __restrict__ outP, size_t psO, int M) {
    // Per k-subtile (20480 u16 = 40 KB): A_h [256][32] @0 (8192);
    // B panels @8192+gate*4096 (r,z,n hi, each [128][32]). Two subtiles = 80 KB.
    __shared__ u16 lds[40960];

    const int tid = threadIdx.x;
    const int lane = tid & 63;
    const int wv = tid >> 6;           // 0..15
    const int wr = wv >> 2;            // 0..3 (64-row group)
    const int wc = wv & 3;             // 0..3 (32-col quarter)
    const int frow = lane & 15;
    const int kg = lane >> 4;
    const int rowBase = blockIdx.x * 256;
    const int colBase = blockIdx.y * 128;

    // staging per subtile: 40 x 1KB issues over 16 waves (up to 3 per wave).
    // q = j*16 + wv; q<16: A sub q; q in [16,40): qb=q-16: gate qb>>3, sub qb&7.
    int offj[3]; int ldsj[3]; bool actj[3]; bool isBj[3];
#pragma unroll
    for (int j = 0; j < 3; ++j) {
        int q = j * 16 + wv;
        actj[j] = q < 40;
        isBj[j] = q >= 16;
        int eoff = 0, ldso = 0;
        if (q < 16) {
            int row = q * 16 + (lane >> 2);
            int chunk = (lane & 3) ^ ((row >> 1) & 3);
            eoff = (rowBase + row) * DD + chunk * 8;
            ldso = q * 512;
        } else if (q < 40) {
            int qb = q - 16;                 // 0..23
            int gate = qb >> 3;              // 0:r 1:z 2:n
            int sub = qb & 7;
            int row = sub * 16 + (lane >> 2);
            int chunk = (lane & 3) ^ ((row >> 1) & 3);
            eoff = (gate * 256 + colBase + row) * DD + chunk * 8;
            ldso = 8192 + qb * 512;
        }
        offj[j] = eoff; ldsj[j] = ldso;
    }

    f32x4 accr[4][2] = {};
    f32x4 accz[4][2] = {};
    f32x4 accx[4][2] = {};
    f32x4 acch[4][2] = {};

#pragma unroll
    for (int half = 0; half < 2; ++half) {
        const u16* Ab = half ? pX : pMsgH;     // hi plane only
        const u16* Bb = half ? pWhhH : pWihH;  // hi plane only
        for (int kc = 0; kc < DD; kc += 2 * BK) {
#pragma unroll
            for (int j = 0; j < 3; ++j)
                if (actj[j]) gload16((isBj[j] ? Bb : Ab) + offj[j] + kc, &lds[ldsj[j]]);
#pragma unroll
            for (int j = 0; j < 3; ++j)
                if (actj[j]) gload16((isBj[j] ? Bb : Ab) + offj[j] + kc + BK,
                                     &lds[20480 + ldsj[j]]);
            __syncthreads();

#pragma unroll
            for (int st = 0; st < 2; ++st) {
                const u16* L = &lds[st * 20480];
                f16x8 af[4];
#pragma unroll
                for (int mf = 0; mf < 4; ++mf) {
                    int row = wr * 64 + mf * 16 + frow;
                    af[mf] = *reinterpret_cast<const f16x8*>(
                        &L[row * 32 + ((kg ^ ((row >> 1) & 3)) * 8)]);
                }
#pragma unroll
                for (int nf = 0; nf < 2; ++nf) {
                    int brow = wc * 32 + nf * 16 + frow;
                    int bsw = brow * 32 + ((kg ^ ((brow >> 1) & 3)) * 8);
                    f16x8 brh = *reinterpret_cast<const f16x8*>(&L[8192 + bsw]);
                    f16x8 bzh = *reinterpret_cast<const f16x8*>(&L[12288 + bsw]);
                    f16x8 bnh = *reinterpret_cast<const f16x8*>(&L[16384 + bsw]);
#pragma unroll
                    for (int mf = 0; mf < 4; ++mf) {
                        accr[mf][nf] = __builtin_amdgcn_mfma_f32_16x16x32_f16(
                            af[mf], brh, accr[mf][nf], 0, 0, 0);
                        accz[mf][nf] = __builtin_amdgcn_mfma_f32_16x16x32_f16(
                            af[mf], bzh, accz[mf][nf], 0, 0, 0);
                        f32x4 cn = (half == 0) ? accx[mf][nf] : acch[mf][nf];
                        cn = __builtin_amdgcn_mfma_f32_16x16x32_f16(af[mf], bnh, cn, 0, 0, 0);
                        if (half == 0) accx[mf][nf] = cn; else acch[mf][nf] = cn;
                    }
                }
            }
            __syncthreads();
        }
    }

    // epilogue: full GRU update (fast transcendentals; x blend from both planes)
#pragma unroll
    for (int nf = 0; nf < 2; ++nf) {
        int gc = colBase + wc * 32 + nf * 16 + frow;
        float br = bih[gc] + bhh[gc];
        float bz = bih[256 + gc] + bhh[256 + gc];
        float bx = bih[512 + gc];
        float bh = bhh[512 + gc];
#pragma unroll
        for (int mf = 0; mf < 4; ++mf) {
#pragma unroll
            for (int j = 0; j < 4; ++j) {
                int gr = rowBase + wr * 64 + mf * 16 + kg * 4 + j;
                if (gr < M) {
                    size_t off = (size_t)gr * DD + gc;
                    float r = fsig(accr[mf][nf][j] + br);
                    float z = fsig(accz[mf][nf][j] + bz);
                    float T = ftanh_(accx[mf][nf][j] + bx + r * (acch[mf][nf][j] + bh));
                    float x = h2f(pX[off]) + h2f(pX[psA + off]);
                    float o = (1.0f - z) * T + z * x;
                    if (FINAL) outF[off] = o;
                    else       store_planes(outP, psO, off, o);
                }
            }
        }
    }
}

// ---------------- segment sum -> msg single fp16 plane ----------------
__global__ __launch_bounds__(256)
void segsum_kernel(const u16* __restrict__ hp, const int* __restrict__ row_ptr,
                   const int* __restrict__ csr_src, u16* __restrict__ msgH, int n) {
    int node = blockIdx.x * 4 + threadIdx.y;
    if (node >= n) return;
    int d4 = threadIdx.x * 4;
    int s = row_ptr[node];
    int e = row_ptr[node + 1];
    float4 acc = make_float4(0.f, 0.f, 0.f, 0.f);
    for (int j = s; j < e; ++j) {
        int sn = csr_src[j];
        f16x4 v = *reinterpret_cast<const f16x4*>(&hp[(size_t)sn * DD + d4]);
        acc.x += (float)v[0]; acc.y += (float)v[1];
        acc.z += (float)v[2]; acc.w += (float)v[3];
    }
    size_t off = (size_t)node * DD + d4;
    *reinterpret_cast<uint2*>(&msgH[off]) =
        make_uint2(pk(f2h(acc.x), f2h(acc.y)), pk(f2h(acc.z), f2h(acc.w)));
}

// ---------------- launch ----------------

extern "C" void kernel_launch(void* const* d_in, const int* in_sizes, int n_in,
                              void* d_out, int out_size, void* d_ws, size_t ws_size,
                              hipStream_t stream) {
    const float* x0  = (const float*)d_in[0];
    const float* W1  = (const float*)d_in[1];
    const float* b1  = (const float*)d_in[2];
    const float* W2  = (const float*)d_in[3];
    const float* b2  = (const float*)d_in[4];
    const float* Wih = (const float*)d_in[5];
    const float* bih = (const float*)d_in[6];
    const float* Whh = (const float*)d_in[7];
    const float* bhh = (const float*)d_in[8];
    const int*   src = (const int*)d_in[9];
    const int*   dst = (const int*)d_in[10];

    // workspace layout (<= proven 211.3 MB footprint)
    char* ws = (char*)d_ws;
    const size_t PSA = (size_t)NNP * DD;
    const size_t SP  = PSA * 2 * sizeof(u16);
    const size_t NB  = PSA * sizeof(float);
    const size_t PSW2 = (size_t)DD * DD;
    const size_t PSW3 = (size_t)3 * DD * DD;
    u16* XP0   = (u16*)(ws);
    u16* XP1   = (u16*)(ws + SP);
    u16* TP    = (u16*)(ws + 2 * SP);       // msg single fp16 plane
    u16* HP    = (u16*)(ws + 3 * SP);       // h single fp16 plane
    u16* W1H   = (u16*)(ws + 3 * SP + NB);  // hi-plane-only weights
    u16* W2H   = W1H + PSW2;
    u16* WIHH  = W2H + PSW2;
    u16* WHHH  = WIHH + PSW3;
    int* counts  = (int*)(WHHH + PSW3);
    int* cursor  = counts + NN;
    int* row_ptr = cursor + NN;
    int* csr     = row_ptr + NN + 8;
    const size_t needed = 3 * SP + NB + (2 * PSW2 + 2 * PSW3) * sizeof(u16)
                        + (size_t)(2 * NN + NN + 9 + NE) * sizeof(int);
    if (ws_size < needed) return;

    float* FOUT = (float*)d_out;

    // CSR build
    zero_kernel<<<(2 * NN + 255) / 256, 256, 0, stream>>>(counts, 2 * NN);
    hist_kernel<<<(NE + 255) / 256, 256, 0, stream>>>(dst, counts, NE);
    scan_kernel<<<1, 1024, 0, stream>>>(counts, row_ptr, NN);
    fill_kernel<<<(NE + 255) / 256, 256, 0, stream>>>(src, dst, row_ptr, cursor, csr, NE);

    // weights: hi plane only; x0: 2-plane split
    half_rows<<<DD, 256, 0, stream>>>(W1, W1H);
    half_rows<<<DD, 256, 0, stream>>>(W2, W2H);
    half_rows<<<3 * DD, 256, 0, stream>>>(Wih, WIHH);
    half_rows<<<3 * DD, 256, 0, stream>>>(Whh, WHHH);
    split_rows<<<NNP, 256, 0, stream>>>(x0, XP0, PSA, NN);

    const dim3 gridGRU((NNP + 255) / 256, 2);   // 196 x 2, 1024-thread blocks

    for (int s = 0; s < NSTEPS; ++s) {
        u16* XPc = (s & 1) ? XP1 : XP0;
        u16* XPn = (s & 1) ? XP0 : XP1;

        // h = MLP(x) -> HP (single fp16 plane)
        mlp_fused<<<NNP / 32, 256, 0, stream>>>(
            XPc, W1H, W2H, b1, b2, HP, NN);
        // msg = segment_sum(h[src], dst) -> TP (single fp16 plane)
        segsum_kernel<<<dim3((NN + 3) / 4), dim3(64, 4), 0, stream>>>(
            HP, row_ptr, csr, TP, NN);
        // full GRU update -> x_next planes (final: fp32 d_out)
        if (s < NSTEPS - 1) {
            gru_fused<false><<<gridGRU, 1024, 0, stream>>>(
                TP, XPc, PSA, WIHH, WHHH, bih, bhh,
                nullptr, XPn, PSA, NN);
        } else {
            gru_fused<true><<<gridGRU, 1024, 0, stream>>>(
                TP, XPc, PSA, WIHH, WHHH, bih, bhh,
                FOUT, nullptr, 0, NN);
        }
    }
}

// Round 23
// 1700.322 us; speedup vs baseline: 1.4403x; 1.4359x over previous
//
#include <hip/hip_runtime.h>
#include <hip/hip_bf16.h>
#include <math.h>

// Problem constants
#define NN 50000
#define NNP 50048       // rows padded to multiple of 128
#define NE 800000
#define DD 256
#define NSTEPS 6

#define BK 32

typedef unsigned short u16;
typedef _Float16 f16x8 __attribute__((ext_vector_type(8)));
typedef _Float16 f16x4 __attribute__((ext_vector_type(4)));
typedef float f32x4 __attribute__((ext_vector_type(4)));

__device__ __forceinline__ float sigmoidf_(float v) {
    return 1.0f / (1.0f + expf(-v));
}
__device__ __forceinline__ u16 f2h(float v) {
    _Float16 h = (_Float16)v;            // RNE
    u16 u; __builtin_memcpy(&u, &h, 2); return u;
}
__device__ __forceinline__ float h2f(u16 u) {
    _Float16 h; __builtin_memcpy(&h, &u, 2); return (float)h;
}
// fp16 2-way split: v ~= h + l to 2^-22 relative
__device__ __forceinline__ void split2(float v, u16& h, u16& l) {
    h = f2h(v);
    float r = v - h2f(h);
    l = f2h(r);
}
__device__ __forceinline__ unsigned pk(u16 a, u16 b) {
    return (unsigned)a | ((unsigned)b << 16);
}
__device__ __forceinline__ void store_planes(u16* base, size_t ps, size_t off, float v) {
    u16 h, l; split2(v, h, l);
    base[off] = h; base[ps + off] = l;
}
__device__ __forceinline__ void gload16(const void* g, void* l) {
    __builtin_amdgcn_global_load_lds(
        (const __attribute__((address_space(1))) void*)g,
        (__attribute__((address_space(3))) void*)l, 16, 0, 0);
}

// ---------------- CSR build (verified R1-R22) ----------------

__global__ void zero_kernel(int* __restrict__ p, int n) {
    int i = blockIdx.x * blockDim.x + threadIdx.x;
    if (i < n) p[i] = 0;
}
__global__ void hist_kernel(const int* __restrict__ dst, int* __restrict__ counts, int E) {
    int e = blockIdx.x * blockDim.x + threadIdx.x;
    if (e < E) atomicAdd(&counts[dst[e]], 1);
}
__global__ void scan_kernel(const int* __restrict__ counts, int* __restrict__ row_ptr, int n) {
    __shared__ int buf[1024];
    __shared__ int carry;
    const int tid = threadIdx.x;
    if (tid == 0) carry = 0;
    __syncthreads();
    for (int base = 0; base < n; base += 1024) {
        int i = base + tid;
        int v = (i < n) ? counts[i] : 0;
        buf[tid] = v;
        __syncthreads();
        for (int off = 1; off < 1024; off <<= 1) {
            int t = (tid >= off) ? buf[tid - off] : 0;
            __syncthreads();
            buf[tid] += t;
            __syncthreads();
        }
        if (i < n) row_ptr[i] = carry + buf[tid] - v;
        __syncthreads();
        if (tid == 0) carry += buf[1023];
        __syncthreads();
    }
    if (threadIdx.x == 0) row_ptr[n] = carry;
}
__global__ void fill_kernel(const int* __restrict__ src, const int* __restrict__ dst,
                            const int* __restrict__ row_ptr, int* __restrict__ cursor,
                            int* __restrict__ csr_src, int E) {
    int e = blockIdx.x * blockDim.x + threadIdx.x;
    if (e < E) {
        int d = dst[e];
        int p = atomicAdd(&cursor[d], 1);
        csr_src[row_ptr[d] + p] = src[e];
    }
}

// ---------------- fp32 -> 2 fp16 planes (rows padded w/ zero) ----------------
__global__ void split_rows(const float* __restrict__ src, u16* __restrict__ dst,
                           size_t pstride, int srcRows) {
    int row = blockIdx.x;
    int col = threadIdx.x;
    size_t off = (size_t)row * DD + col;
    float v = (row < srcRows) ? src[off] : 0.0f;
    store_planes(dst, pstride, off, v);
}

// ---------------- fp32 -> single fp16 plane ----------------
__global__ void half_rows(const float* __restrict__ src, u16* __restrict__ dst) {
    int row = blockIdx.x;
    int col = threadIdx.x;
    size_t off = (size_t)row * DD + col;
    dst[off] = f2h(src[off]);
}

// ---------------- fused MLP, 1-term products (R18 champion, 32-row blocks) ----------------
// t1 = ReLU(xh @ W1h^T + b1) [fp16 in LDS]; h = t1 @ W2h^T + b2 -> fp16 HP.
__global__ __launch_bounds__(256, 3)
void mlp_fused(const u16* __restrict__ pX,
               const u16* __restrict__ W1H, const u16* __restrict__ W2H,
               const float* __restrict__ b1, const float* __restrict__ b2,
               u16* __restrict__ HP, int M) {
    // LDS (u16): A_h 2 subtiles @0 (1024); W 16 subtiles @1024 (8192);
    // t1 [32][256] swizzled @9216 (8192). Total 17408 u16 = 34.8 KB.
    __shared__ u16 lds[17408];
    const int T1B = 9216;

    const int tid = threadIdx.x;
    const int lane = tid & 63;
    const int wv = tid >> 6;           // col quarter 0..3
    const int frow = lane & 15;
    const int kg = lane >> 4;
    const int rowBase = blockIdx.x * 32;

    // staging: 18 x 1KB issues per k-iter, up to 5 per wave.
    int offj[5]; int ldsj[5]; bool isWj[5]; bool actj[5];
#pragma unroll
    for (int j = 0; j < 5; ++j) {
        int q = wv * 5 + j;
        actj[j] = q < 18;
        bool isW = q >= 2;
        int row, ldso, eoff = 0;
        if (q < 2) {
            row = q * 16 + (lane >> 2);
            int chunk = (lane & 3) ^ ((row >> 1) & 3);
            eoff = (rowBase + row) * DD + chunk * 8;
            ldso = q * 512;
        } else {
            int qw = (q - 2) & 15;
            row = qw * 16 + (lane >> 2);
            int chunk = (lane & 3) ^ ((row >> 1) & 3);
            eoff = row * DD + chunk * 8;
            ldso = 1024 + qw * 512;
        }
        offj[j] = eoff; ldsj[j] = ldso; isWj[j] = isW;
    }

    // phase 1: t1 = ReLU(xh @ W1h^T + b1)
    f32x4 acc1[2][4] = {};
    for (int kc = 0; kc < DD; kc += BK) {
#pragma unroll
        for (int j = 0; j < 5; ++j)
            if (actj[j]) gload16((isWj[j] ? W1H : pX) + offj[j] + kc, &lds[ldsj[j]]);
        __syncthreads();

        f16x8 af[2];
#pragma unroll
        for (int mf = 0; mf < 2; ++mf) {
            int row = mf * 16 + frow;
            af[mf] = *reinterpret_cast<const f16x8*>(
                &lds[row * 32 + ((kg ^ ((row >> 1) & 3)) * 8)]);
        }
#pragma unroll
        for (int nf = 0; nf < 4; ++nf) {
            int brow = wv * 64 + nf * 16 + frow;
            int boff = 1024 + brow * 32 + ((kg ^ ((brow >> 1) & 3)) * 8);
            f16x8 bh = *reinterpret_cast<const f16x8*>(&lds[boff]);
#pragma unroll
            for (int mf = 0; mf < 2; ++mf)
                acc1[mf][nf] = __builtin_amdgcn_mfma_f32_16x16x32_f16(
                    af[mf], bh, acc1[mf][nf], 0, 0, 0);
        }
        __syncthreads();
    }

    // t1 -> LDS fp16 (swizzled: chunk index XOR (row&7))
#pragma unroll
    for (int nf = 0; nf < 4; ++nf) {
        int col = wv * 64 + nf * 16 + frow;
        float bb = b1[col];
        int c8 = col >> 3, ci = col & 7;
#pragma unroll
        for (int mf = 0; mf < 2; ++mf) {
#pragma unroll
            for (int j = 0; j < 4; ++j) {
                int row = mf * 16 + kg * 4 + j;
                float v = fmaxf(acc1[mf][nf][j] + bb, 0.0f);
                lds[T1B + row * 256 + ((c8 ^ (row & 7)) * 8) + ci] = f2h(v);
            }
        }
    }
    __syncthreads();

    // phase 2: h = t1 @ W2h^T + b2 (1-term)
    f32x4 acc2[2][4] = {};
    for (int kc = 0; kc < DD; kc += BK) {
#pragma unroll
        for (int j = 0; j < 5; ++j)
            if (actj[j] && isWj[j]) gload16(W2H + offj[j] + kc, &lds[ldsj[j]]);
        __syncthreads();

        f16x8 at[2];
#pragma unroll
        for (int mf = 0; mf < 2; ++mf) {
            int row = mf * 16 + frow;
            int qc = (kc >> 3) + kg;
            at[mf] = *reinterpret_cast<const f16x8*>(
                &lds[T1B + row * 256 + ((qc ^ (row & 7)) * 8)]);
        }
#pragma unroll
        for (int nf = 0; nf < 4; ++nf) {
            int brow = wv * 64 + nf * 16 + frow;
            int boff = 1024 + brow * 32 + ((kg ^ ((brow >> 1) & 3)) * 8);
            f16x8 bh = *reinterpret_cast<const f16x8*>(&lds[boff]);
#pragma unroll
            for (int mf = 0; mf < 2; ++mf)
                acc2[mf][nf] = __builtin_amdgcn_mfma_f32_16x16x32_f16(
                    at[mf], bh, acc2[mf][nf], 0, 0, 0);
        }
        __syncthreads();
    }

#pragma unroll
    for (int nf = 0; nf < 4; ++nf) {
        int col = wv * 64 + nf * 16 + frow;
        float bb = b2[col];
#pragma unroll
        for (int mf = 0; mf < 2; ++mf) {
#pragma unroll
            for (int j = 0; j < 4; ++j) {
                int gr = rowBase + mf * 16 + kg * 4 + j;
                if (gr < M) HP[(size_t)gr * DD + col] = f2h(acc2[mf][nf][j] + bb);
            }
        }
    }
}

// ---------------- fused GRU: all gates 1-term, 2-subtile k-iter (R18 champion) ----------------
// r = ah*Brh, z = ah*Bzh, n = ah*Bnh (each 1 MFMA) -> 24 MFMA/wave/k-iter.
// LDS 64 KB (2 subtiles x {A_h, r-hi, z-hi, n-hi}); 512 thr, 2 blocks/CU.
template <bool FINAL>
__global__ __launch_bounds__(512, 2)
void gru_fused(const u16* __restrict__ pMsgH, const u16* __restrict__ pX, size_t psA,
               const u16* __restrict__ pWihH, const u16* __restrict__ pWhhH,
               const float* __restrict__ bih, const float* __restrict__ bhh,
               float* __restrict__ outF, u16* __restrict__ outP, size_t psO, int M) {
    __shared__ u16 lds[32768];

    const int tid = threadIdx.x;
    const int lane = tid & 63;
    const int wv = tid >> 6;           // 0..7
    const int wr = wv >> 2;            // 0..1 (64-row half)
    const int wc = wv & 3;             // 0..3 (32-col quarter)
    const int frow = lane & 15;
    const int kg = lane >> 4;
    const int rowBase = blockIdx.x * 128;
    const int colBase = blockIdx.y * 128;

    int offj[4]; int ldsj[4]; bool isBj[4];
#pragma unroll
    for (int j = 0; j < 4; ++j) {
        int q = wv * 4 + j;
        bool isB = q >= 8;
        int eoff, ldso;
        if (!isB) {
            int row = q * 16 + (lane >> 2);
            int chunk = (lane & 3) ^ ((row >> 1) & 3);
            eoff = (rowBase + row) * DD + chunk * 8;
            ldso = q * 512;
        } else {
            int qb = q - 8;                  // 0..23
            int gate = qb >> 3;              // 0:r 1:z 2:n
            int sub = qb & 7;
            int row = sub * 16 + (lane >> 2);
            int chunk = (lane & 3) ^ ((row >> 1) & 3);
            eoff = (gate * 256 + colBase + row) * DD + chunk * 8;
            ldso = 4096 + qb * 512;
        }
        offj[j] = eoff; ldsj[j] = ldso; isBj[j] = isB;
    }

    f32x4 accr[4][2] = {};
    f32x4 accz[4][2] = {};
    f32x4 accx[4][2] = {};
    f32x4 acch[4][2] = {};

#pragma unroll
    for (int half = 0; half < 2; ++half) {
        const u16* Ab = half ? pX : pMsgH;     // hi plane only
        const u16* Bb = half ? pWhhH : pWihH;  // hi plane only
        for (int kc = 0; kc < DD; kc += 2 * BK) {
#pragma unroll
            for (int j = 0; j < 4; ++j)
                gload16((isBj[j] ? Bb : Ab) + offj[j] + kc, &lds[ldsj[j]]);
#pragma unroll
            for (int j = 0; j < 4; ++j)
                gload16((isBj[j] ? Bb : Ab) + offj[j] + kc + BK, &lds[16384 + ldsj[j]]);
            __syncthreads();

#pragma unroll
            for (int st = 0; st < 2; ++st) {
                const u16* L = &lds[st * 16384];
                f16x8 af[4];
#pragma unroll
                for (int mf = 0; mf < 4; ++mf) {
                    int row = wr * 64 + mf * 16 + frow;
                    af[mf] = *reinterpret_cast<const f16x8*>(
                        &L[row * 32 + ((kg ^ ((row >> 1) & 3)) * 8)]);
                }
#pragma unroll
                for (int nf = 0; nf < 2; ++nf) {
                    int brow = wc * 32 + nf * 16 + frow;
                    int bsw = brow * 32 + ((kg ^ ((brow >> 1) & 3)) * 8);
                    f16x8 brh = *reinterpret_cast<const f16x8*>(&L[4096 + bsw]);
                    f16x8 bzh = *reinterpret_cast<const f16x8*>(&L[8192 + bsw]);
                    f16x8 bnh = *reinterpret_cast<const f16x8*>(&L[12288 + bsw]);
#pragma unroll
                    for (int mf = 0; mf < 4; ++mf) {
                        accr[mf][nf] = __builtin_amdgcn_mfma_f32_16x16x32_f16(
                            af[mf], brh, accr[mf][nf], 0, 0, 0);
                        accz[mf][nf] = __builtin_amdgcn_mfma_f32_16x16x32_f16(
                            af[mf], bzh, accz[mf][nf], 0, 0, 0);
                        f32x4 cn = (half == 0) ? accx[mf][nf] : acch[mf][nf];
                        cn = __builtin_amdgcn_mfma_f32_16x16x32_f16(af[mf], bnh, cn, 0, 0, 0);
                        if (half == 0) accx[mf][nf] = cn; else acch[mf][nf] = cn;
                    }
                }
            }
            __syncthreads();
        }
    }

    // epilogue: full GRU update (x blend uses both planes — full precision carry)
#pragma unroll
    for (int nf = 0; nf < 2; ++nf) {
        int gc = colBase + wc * 32 + nf * 16 + frow;
        float br = bih[gc] + bhh[gc];
        float bz = bih[256 + gc] + bhh[256 + gc];
        float bx = bih[512 + gc];
        float bh = bhh[512 + gc];
#pragma unroll
        for (int mf = 0; mf < 4; ++mf) {
#pragma unroll
            for (int j = 0; j < 4; ++j) {
                int gr = rowBase + wr * 64 + mf * 16 + kg * 4 + j;
                if (gr < M) {
                    size_t off = (size_t)gr * DD + gc;
                    float r = sigmoidf_(accr[mf][nf][j] + br);
                    float z = sigmoidf_(accz[mf][nf][j] + bz);
                    float T = tanhf(accx[mf][nf][j] + bx + r * (acch[mf][nf][j] + bh));
                    float x = h2f(pX[off]) + h2f(pX[psA + off]);
                    float o = (1.0f - z) * T + z * x;
                    if (FINAL) outF[off] = o;
                    else       store_planes(outP, psO, off, o);
                }
            }
        }
    }
}

// ---------------- segment sum -> msg single fp16 plane ----------------
__global__ __launch_bounds__(256)
void segsum_kernel(const u16* __restrict__ hp, const int* __restrict__ row_ptr,
                   const int* __restrict__ csr_src, u16* __restrict__ msgH, int n) {
    int node = blockIdx.x * 4 + threadIdx.y;
    if (node >= n) return;
    int d4 = threadIdx.x * 4;
    int s = row_ptr[node];
    int e = row_ptr[node + 1];
    float4 acc = make_float4(0.f, 0.f, 0.f, 0.f);
    for (int j = s; j < e; ++j) {
        int sn = csr_src[j];
        f16x4 v = *reinterpret_cast<const f16x4*>(&hp[(size_t)sn * DD + d4]);
        acc.x += (float)v[0]; acc.y += (float)v[1];
        acc.z += (float)v[2]; acc.w += (float)v[3];
    }
    size_t off = (size_t)node * DD + d4;
    *reinterpret_cast<uint2*>(&msgH[off]) =
        make_uint2(pk(f2h(acc.x), f2h(acc.y)), pk(f2h(acc.z), f2h(acc.w)));
}

// ---------------- launch ----------------

extern "C" void kernel_launch(void* const* d_in, const int* in_sizes, int n_in,
                              void* d_out, int out_size, void* d_ws, size_t ws_size,
                              hipStream_t stream) {
    const float* x0  = (const float*)d_in[0];
    const float* W1  = (const float*)d_in[1];
    const float* b1  = (const float*)d_in[2];
    const float* W2  = (const float*)d_in[3];
    const float* b2  = (const float*)d_in[4];
    const float* Wih = (const float*)d_in[5];
    const float* bih = (const float*)d_in[6];
    const float* Whh = (const float*)d_in[7];
    const float* bhh = (const float*)d_in[8];
    const int*   src = (const int*)d_in[9];
    const int*   dst = (const int*)d_in[10];

    // workspace layout (<= proven 211.3 MB footprint)
    char* ws = (char*)d_ws;
    const size_t PSA = (size_t)NNP * DD;
    const size_t SP  = PSA * 2 * sizeof(u16);
    const size_t NB  = PSA * sizeof(float);
    const size_t PSW2 = (size_t)DD * DD;
    const size_t PSW3 = (size_t)3 * DD * DD;
    u16* XP0   = (u16*)(ws);
    u16* XP1   = (u16*)(ws + SP);
    u16* TP    = (u16*)(ws + 2 * SP);       // msg single fp16 plane
    u16* HP    = (u16*)(ws + 3 * SP);       // h single fp16 plane
    u16* W1H   = (u16*)(ws + 3 * SP + NB);  // hi-plane-only weights
    u16* W2H   = W1H + PSW2;
    u16* WIHH  = W2H + PSW2;
    u16* WHHH  = WIHH + PSW3;
    int* counts  = (int*)(WHHH + PSW3);
    int* cursor  = counts + NN;
    int* row_ptr = cursor + NN;
    int* csr     = row_ptr + NN + 8;
    const size_t needed = 3 * SP + NB + (2 * PSW2 + 2 * PSW3) * sizeof(u16)
                        + (size_t)(2 * NN + NN + 9 + NE) * sizeof(int);
    if (ws_size < needed) return;

    float* FOUT = (float*)d_out;

    // CSR build
    zero_kernel<<<(2 * NN + 255) / 256, 256, 0, stream>>>(counts, 2 * NN);
    hist_kernel<<<(NE + 255) / 256, 256, 0, stream>>>(dst, counts, NE);
    scan_kernel<<<1, 1024, 0, stream>>>(counts, row_ptr, NN);
    fill_kernel<<<(NE + 255) / 256, 256, 0, stream>>>(src, dst, row_ptr, cursor, csr, NE);

    // weights: hi plane only; x0: 2-plane split
    half_rows<<<DD, 256, 0, stream>>>(W1, W1H);
    half_rows<<<DD, 256, 0, stream>>>(W2, W2H);
    half_rows<<<3 * DD, 256, 0, stream>>>(Wih, WIHH);
    half_rows<<<3 * DD, 256, 0, stream>>>(Whh, WHHH);
    split_rows<<<NNP, 256, 0, stream>>>(x0, XP0, PSA, NN);

    const dim3 gridGRU(NNP / 128, 2);   // 391 x 2, 512-thread blocks

    for (int s = 0; s < NSTEPS; ++s) {
        u16* XPc = (s & 1) ? XP1 : XP0;
        u16* XPn = (s & 1) ? XP0 : XP1;

        // h = MLP(x) -> HP (single fp16 plane)
        mlp_fused<<<NNP / 32, 256, 0, stream>>>(
            XPc, W1H, W2H, b1, b2, HP, NN);
        // msg = segment_sum(h[src], dst) -> TP (single fp16 plane)
        segsum_kernel<<<dim3((NN + 3) / 4), dim3(64, 4), 0, stream>>>(
            HP, row_ptr, csr, TP, NN);
        // full GRU update -> x_next planes (final: fp32 d_out)
        if (s < NSTEPS - 1) {
            gru_fused<false><<<gridGRU, 512, 0, stream>>>(
                TP, XPc, PSA, WIHH, WHHH, bih, bhh,
                nullptr, XPn, PSA, NN);
        } else {
            gru_fused<true><<<gridGRU, 512, 0, stream>>>(
                TP, XPc, PSA, WIHH, WHHH, bih, bhh,
                FOUT, nullptr, 0, NN);
        }
    }
}